// Round 6
// baseline (155.366 us; speedup 1.0000x reference)
//
#include <hip/hip_runtime.h>
#include <hip/hip_bf16.h>

#define B 128
#define N 1024
#define L 512
#define D 64
#define NWG 1536

typedef float f32x4 __attribute__((ext_vector_type(4)));
typedef short bf16x8 __attribute__((ext_vector_type(8)));

// 8 fp32 -> 8 bf16 (RNE) via packed HW cvt
__device__ inline bf16x8 cvt8(float4 f0, float4 f1) {
    union { __hip_bfloat162 h2[4]; bf16x8 v; } u;
    u.h2[0] = __float22bfloat162_rn(make_float2(f0.x, f0.y));
    u.h2[1] = __float22bfloat162_rn(make_float2(f0.z, f0.w));
    u.h2[2] = __float22bfloat162_rn(make_float2(f1.x, f1.y));
    u.h2[3] = __float22bfloat162_rn(make_float2(f1.z, f1.w));
    return u.v;
}

// async global->LDS DMA, 16B per lane; LDS dest must be linear base+lane*16
__device__ __forceinline__ void gload16(const void* g, void* l) {
    __builtin_amdgcn_global_load_lds(
        (const __attribute__((address_space(1))) void*)g,
        (__attribute__((address_space(3))) void*)l, 16, 0, 0);
}

// ============================ bf16-workspace path ============================
// Fused pre-pass: blocks [0,B): mask counts; blocks [B,B+512): I fp32->bf16.
// Also zeroes the sim completion counter (ws is poisoned between iterations).
__global__ __launch_bounds__(256) void prep_kernel(
        const float* __restrict__ tmask, const float* __restrict__ imask,
        const float* __restrict__ I,
        int* __restrict__ counts, unsigned short* __restrict__ Ibf,
        unsigned int* __restrict__ done) {
    int blk = blockIdx.x, tid = threadIdx.x;
    if (blk < B) {
        int b = blk;
        int w = tid >> 6, lane = tid & 63;
        if (blk == 0 && tid == 2) *done = 0u;
        float ts = 0.f, is = 0.f;
        const float* tm = tmask + (size_t)b * N;
#pragma unroll
        for (int i = 0; i < N / 256; ++i) ts += tm[tid + i * 256];
        const float* im = imask + (size_t)b * L;
#pragma unroll
        for (int i = 0; i < L / 256; ++i) is += im[tid + i * 256];
        for (int off = 32; off; off >>= 1) {
            ts += __shfl_down(ts, off);
            is += __shfl_down(is, off);
        }
        __shared__ float red[8];
        if (lane == 0) { red[w] = ts; red[4 + w] = is; }
        __syncthreads();
        if (tid == 0) counts[b]     = (int)(red[0] + red[1] + red[2] + red[3] + 0.5f);
        if (tid == 1) counts[B + b] = (int)(red[4] + red[5] + red[6] + red[7] + 0.5f);
    } else {
        // 512 blocks x 256 thr x 4 chunks of 8 elems = 4,194,304 elems exactly
        int t = (blk - B) * 256 + tid;                 // 0..131071
#pragma unroll
        for (int j = 0; j < 4; ++j) {
            size_t ci = (size_t)t + (size_t)j * 131072;
            const float4* p = (const float4*)(I + ci * 8);
            *(bf16x8*)(Ibf + ci * 8) = cvt8(p[0], p[1]);
        }
    }
}

// grid = 1536 blocks x 256 thr. vs round-5:
//  - XCD swizzle: work=(hw&7)*192+(hw>>3) puts the 4 token-chunk blocks of one
//    (s,b) — which read the SAME Ibf[b] 64KB — on one XCD's L2 (fetch dedup +
//    L2-hit staging latency)
//  - single-round-trip prologue: stage(0)/stage(1) DMA issued BEFORE afrag
//    loads; one vmcnt(0) drain; steady loop = proven vmcnt(2) 3-buffer ledger
//  - loss fused: per-block release (threadfence+atomicAdd); last block (old==
//    NWG-1) acquires and folds partials -> hinge -> out. No early return; all
//    blocks converge to the tail so any block can be the folder.
__global__ __launch_bounds__(256, 4) void sim_kernel_bf16(
        const float* __restrict__ T, const unsigned short* __restrict__ Ibf,
        const int* __restrict__ counts,
        const int* __restrict__ Iimp, const int* __restrict__ Simp,
        float* __restrict__ partials, unsigned int* __restrict__ done,
        float* __restrict__ out) {
    int hw = blockIdx.x;                   // 0..1535
    int work = (hw & 7) * 192 + (hw >> 3); // bijective XCD grouping
    int chunk = work & 3;
    int bs = work >> 2;
    int b = bs & (B - 1);
    int s = bs >> 7;
    int Tb = b, Ib = b;
    if (s == 1) Tb = Simp[b];
    else if (s == 2) Ib = Iimp[b];

    int tid = threadIdx.x;
    int w = tid >> 6;
    int lane = tid & 63;
    int q = lane >> 4;
    int c = lane & 15;

    int ntok = counts[Tb];         // block-uniform
    int nreg = counts[B + Ib];

    int tok0 = chunk << 8;
    bool active = (chunk == 0) || (tok0 < ntok);   // ntok >= 256 always

    __shared__ unsigned short ldsI[3][4096];     // 3 x 8 KB bf16 chunk buffers
    __shared__ float red[4];
    __shared__ int lastflag;
    __shared__ float w4[4];

    if (active) {
        // ---- staging decode: 2 x 16B DMA per thread per chunk ----
        // 16B chunk ci in [0,512): g=ci>>6 (=rt*2+h), ln=ci&63:
        //   region (g>>1)*16+(ln&15), elems (g&1)*32+(ln>>4)*8 .. +8
        int rloc[2], eoff[2];
#pragma unroll
        for (int j = 0; j < 2; ++j) {
            int ci = tid + j * 256;
            int g = ci >> 6, ln = ci & 63;
            rloc[j] = (g >> 1) * 16 + (ln & 15);
            eoff[j] = (g & 1) * 32 + (ln >> 4) * 8;
        }
        const unsigned short* Ibase = Ibf + (size_t)Ib * L * D;
        int nchunks = (nreg + 63) >> 6;          // always >= 2 (nreg >= 128)
        int nregm1 = nreg - 1;

        auto stage = [&](int k) {
            unsigned short* buf = &ldsI[k % 3][0];
            int rbase = k << 6;
#pragma unroll
            for (int j = 0; j < 2; ++j) {
                int r = rbase + rloc[j];
                if (r > nregm1) r = nregm1;      // duplicate valid row: max-neutral
                gload16(Ibase + (size_t)r * D + eoff[j], buf + (size_t)(tid + j * 256) * 8);
            }
        };

        stage(0);                                // DMA first: overlaps afrag loads
        stage(1);

        // ---- A fragments: 4 token tiles x 2 K-halves (rows>=ntok masked at sum)
        int wt0 = tok0 + w * 64;
        bf16x8 afrag[4][2];
#pragma unroll
        for (int tt = 0; tt < 4; ++tt) {
            const float* trow = T + ((size_t)Tb * N + wt0 + tt * 16 + c) * D;
#pragma unroll
            for (int h = 0; h < 2; ++h) {
                const float4* p = (const float4*)(trow + h * 32 + q * 8);
                afrag[tt][h] = cvt8(p[0], p[1]);
            }
        }

        float mx[4][4];
#pragma unroll
        for (int tt = 0; tt < 4; ++tt)
#pragma unroll
            for (int i = 0; i < 4; ++i) mx[tt][i] = -3.0e38f;

        // single prologue drain: afrag + stage(0..1) in one HBM round trip
        asm volatile("s_waitcnt vmcnt(0)" ::: "memory");
        __builtin_amdgcn_s_barrier();

        for (int k = 0; k < nchunks; ++k) {
            if (k + 2 < nchunks) stage(k + 2);   // depth-2: issue over compute

            // full 64-region chunk: 8 ds_read_b128 (conflict-free) + 32 MFMA
            const char* base = (const char*)&ldsI[k % 3][0] + (size_t)lane * 16;
#pragma unroll
            for (int rt = 0; rt < 4; ++rt) {
                bf16x8 b0 = *(const bf16x8*)(base + (rt * 2 + 0) * 1024);
                bf16x8 b1 = *(const bf16x8*)(base + (rt * 2 + 1) * 1024);
#pragma unroll
                for (int tt = 0; tt < 4; ++tt) {
                    f32x4 acc = {0.f, 0.f, 0.f, 0.f};
                    acc = __builtin_amdgcn_mfma_f32_16x16x32_bf16(afrag[tt][0], b0, acc, 0, 0, 0);
                    acc = __builtin_amdgcn_mfma_f32_16x16x32_bf16(afrag[tt][1], b1, acc, 0, 0, 0);
#pragma unroll
                    for (int i = 0; i < 4; ++i) mx[tt][i] = fmaxf(mx[tt][i], acc[i]);
                }
            }

            if (k + 1 < nchunks) {
                // need stage(k+1) landed; stage(k+2) (2 ops) may stay in flight
                if (k + 2 < nchunks)
                    asm volatile("s_waitcnt vmcnt(2) lgkmcnt(0)" ::: "memory");
                else
                    asm volatile("s_waitcnt vmcnt(0) lgkmcnt(0)" ::: "memory");
                __builtin_amdgcn_s_barrier();
            }
        }

        // ---- cross-lane max over 16 region-cols ----
#pragma unroll
        for (int m = 1; m < 16; m <<= 1) {
#pragma unroll
            for (int tt = 0; tt < 4; ++tt)
#pragma unroll
                for (int i = 0; i < 4; ++i)
                    mx[tt][i] = fmaxf(mx[tt][i], __shfl_xor(mx[tt][i], m));
        }

        // ---- masked token sum (C layout: row = q*4 + i) ----
        float bsum = 0.f;
        if (c == 0) {
#pragma unroll
            for (int tt = 0; tt < 4; ++tt)
#pragma unroll
                for (int i = 0; i < 4; ++i) {
                    int row = wt0 + tt * 16 + q * 4 + i;
                    if (row < ntok) bsum += mx[tt][i];
                }
        }
        for (int off = 32; off; off >>= 1) bsum += __shfl_down(bsum, off);
        if (lane == 0) red[w] = bsum;
        __syncthreads();
    }

    // ---- common tail: publish partial, last block folds the loss ----
    if (tid == 0) {
        float val = active ? (red[0] + red[1] + red[2] + red[3]) / (float)ntok : 0.f;
        partials[work] = val;                    // logical (s,b,chunk) order
        __threadfence();                         // release partials
        unsigned int old = atomicAdd(done, 1u);
        lastflag = (old == NWG - 1) ? 1 : 0;
    }
    __syncthreads();
    if (lastflag) {
        __threadfence();                         // acquire all partials
        float per = 0.f;
        if (tid < B) {
            const float4* p4 = (const float4*)partials;
            float4 a4 = p4[tid], s4 = p4[B + tid], i4 = p4[2 * B + tid];
            float anc = a4.x + a4.y + a4.z + a4.w;
            float smp = s4.x + s4.y + s4.z + s4.w;
            float imp = i4.x + i4.y + i4.z + i4.w;
            per = fmaxf(1.f + imp - anc, 0.f) + fmaxf(1.f + smp - anc, 0.f);
        }
        for (int off = 32; off; off >>= 1) per += __shfl_down(per, off);
        if ((tid & 63) == 0) w4[tid >> 6] = per;
        __syncthreads();
        if (tid == 0) out[0] = (w4[0] + w4[1] + w4[2] + w4[3]) / (float)B;
    }
}

// ===================== fallback path (tiny workspace, r3) =====================
__global__ __launch_bounds__(256) void count_kernel(
        const float* __restrict__ tmask, const float* __restrict__ imask,
        int* __restrict__ counts) {
    int b = blockIdx.x, tid = threadIdx.x;
    int w = tid >> 6, lane = tid & 63;
    float ts = 0.f, is = 0.f;
    const float* tm = tmask + (size_t)b * N;
#pragma unroll
    for (int i = 0; i < N / 256; ++i) ts += tm[tid + i * 256];
    const float* im = imask + (size_t)b * L;
#pragma unroll
    for (int i = 0; i < L / 256; ++i) is += im[tid + i * 256];
    for (int off = 32; off; off >>= 1) {
        ts += __shfl_down(ts, off);
        is += __shfl_down(is, off);
    }
    __shared__ float red[8];
    if (lane == 0) { red[w] = ts; red[4 + w] = is; }
    __syncthreads();
    if (tid == 0) counts[b]     = (int)(red[0] + red[1] + red[2] + red[3] + 0.5f);
    if (tid == 1) counts[B + b] = (int)(red[4] + red[5] + red[6] + red[7] + 0.5f);
}

// verbatim round-3 sim kernel (passed): fp32 DMA staging, 3x16KB LDS
__global__ __launch_bounds__(256, 3) void sim_kernel_f32(
        const float* __restrict__ T, const float* __restrict__ I,
        const int* __restrict__ counts,
        const int* __restrict__ Iimp, const int* __restrict__ Simp,
        float* __restrict__ partials) {
    int blk = blockIdx.x;
    int chunk = blk & 3;
    int bs = blk >> 2;
    int b = bs & (B - 1);
    int s = bs >> 7;
    int Tb = b, Ib = b;
    if (s == 1) Tb = Simp[b];
    else if (s == 2) Ib = Iimp[b];

    int tid = threadIdx.x;
    int w = tid >> 6;
    int lane = tid & 63;
    int q = lane >> 4;
    int c = lane & 15;

    int ntok = counts[Tb];
    int nreg = counts[B + Ib];

    int tok0 = chunk << 8;
    if (chunk != 0 && tok0 >= ntok) {
        if (tid == 0) partials[blk] = 0.f;
        return;
    }

    __shared__ float ldsI[3][4096];
    __shared__ float red[4];

    int wt0 = tok0 + w * 64;
    bf16x8 afrag[4][2];
#pragma unroll
    for (int tt = 0; tt < 4; ++tt) {
        const float* trow = T + ((size_t)Tb * N + wt0 + tt * 16 + c) * D;
#pragma unroll
        for (int h = 0; h < 2; ++h) {
            const float4* p = (const float4*)(trow + h * 32 + q * 8);
            afrag[tt][h] = cvt8(p[0], p[1]);
        }
    }

    float mx[4][4];
#pragma unroll
    for (int tt = 0; tt < 4; ++tt)
#pragma unroll
        for (int i = 0; i < 4; ++i) mx[tt][i] = -3.0e38f;

    int rloc[4], foff[4];
#pragma unroll
    for (int j = 0; j < 4; ++j) {
        int ci = tid + j * 256;
        int fh = ci >> 7, idx = ci & 127, half = idx >> 6, ln2 = idx & 63;
        rloc[j] = (fh >> 1) * 16 + (ln2 & 15);
        foff[j] = (fh & 1) * 32 + (ln2 >> 4) * 8 + half * 4;
    }
    const float* Ibase = I + (size_t)Ib * L * D;
    int nchunks = (nreg + 63) >> 6;
    int nregm1 = nreg - 1;

    auto stage = [&](int k) {
        float* buf = &ldsI[k % 3][0];
        int rbase = k << 6;
#pragma unroll
        for (int j = 0; j < 4; ++j) {
            int r = rbase + rloc[j];
            if (r > nregm1) r = nregm1;
            gload16(Ibase + (size_t)r * D + foff[j], buf + (tid + j * 256) * 4);
        }
    };

    asm volatile("s_waitcnt vmcnt(0)" ::: "memory");
    stage(0);
    stage(1);
    asm volatile("s_waitcnt vmcnt(4)" ::: "memory");
    __builtin_amdgcn_s_barrier();

    for (int k = 0; k < nchunks; ++k) {
        if (k + 2 < nchunks) stage(k + 2);

        const char* base = (const char*)&ldsI[k % 3][0] + (size_t)lane * 16;
#pragma unroll
        for (int rt = 0; rt < 4; ++rt) {
            float4 e0 = *(const float4*)(base + (rt * 2 + 0) * 2048);
            float4 e1 = *(const float4*)(base + (rt * 2 + 0) * 2048 + 1024);
            float4 e2 = *(const float4*)(base + (rt * 2 + 1) * 2048);
            float4 e3 = *(const float4*)(base + (rt * 2 + 1) * 2048 + 1024);
            bf16x8 b0 = cvt8(e0, e1);
            bf16x8 b1 = cvt8(e2, e3);
#pragma unroll
            for (int tt = 0; tt < 4; ++tt) {
                f32x4 acc = {0.f, 0.f, 0.f, 0.f};
                acc = __builtin_amdgcn_mfma_f32_16x16x32_bf16(afrag[tt][0], b0, acc, 0, 0, 0);
                acc = __builtin_amdgcn_mfma_f32_16x16x32_bf16(afrag[tt][1], b1, acc, 0, 0, 0);
#pragma unroll
                for (int i = 0; i < 4; ++i) mx[tt][i] = fmaxf(mx[tt][i], acc[i]);
            }
        }

        if (k + 1 < nchunks) {
            if (k + 2 < nchunks)
                asm volatile("s_waitcnt vmcnt(4) lgkmcnt(0)" ::: "memory");
            else
                asm volatile("s_waitcnt vmcnt(0) lgkmcnt(0)" ::: "memory");
            __builtin_amdgcn_s_barrier();
        }
    }

#pragma unroll
    for (int m = 1; m < 16; m <<= 1) {
#pragma unroll
        for (int tt = 0; tt < 4; ++tt)
#pragma unroll
            for (int i = 0; i < 4; ++i)
                mx[tt][i] = fmaxf(mx[tt][i], __shfl_xor(mx[tt][i], m));
    }

    float bsum = 0.f;
    if (c == 0) {
#pragma unroll
        for (int tt = 0; tt < 4; ++tt)
#pragma unroll
            for (int i = 0; i < 4; ++i) {
                int row = wt0 + tt * 16 + q * 4 + i;
                if (row < ntok) bsum += mx[tt][i];
            }
    }
    for (int off = 32; off; off >>= 1) bsum += __shfl_down(bsum, off);
    if (lane == 0) red[w] = bsum;
    __syncthreads();
    if (tid == 0)
        partials[blk] = (red[0] + red[1] + red[2] + red[3]) / (float)ntok;
}

// 1 block x 384 threads (fallback path only)
__global__ void loss_kernel(const float* __restrict__ partials,
                            float* __restrict__ out) {
    int tid = threadIdx.x;  // 0..383
    __shared__ float simsL[384];
    __shared__ float w6[6];
    const float4* p4 = (const float4*)partials;
    float4 v = p4[tid];
    simsL[tid] = v.x + v.y + v.z + v.w;
    __syncthreads();
    float per = 0.f;
    if (tid < B) {
        float anc  = simsL[tid];
        float simp = simsL[B + tid];
        float iimp = simsL[2 * B + tid];
        per = fmaxf(1.f + iimp - anc, 0.f) + fmaxf(1.f + simp - anc, 0.f);
    }
    for (int off = 32; off; off >>= 1) per += __shfl_down(per, off);
    if ((tid & 63) == 0) w6[tid >> 6] = per;
    __syncthreads();
    if (tid == 0)
        out[0] = (w6[0] + w6[1] + w6[2] + w6[3] + w6[4] + w6[5]) / (float)B;
}

extern "C" void kernel_launch(void* const* d_in, const int* in_sizes, int n_in,
                              void* d_out, int out_size, void* d_ws, size_t ws_size,
                              hipStream_t stream) {
    const float* T     = (const float*)d_in[0];
    const float* I     = (const float*)d_in[1];
    const float* tmask = (const float*)d_in[2];
    const float* imask = (const float*)d_in[3];
    const int*   Iimp  = (const int*)d_in[4];
    const int*   Simp  = (const int*)d_in[5];
    // ws: counts[256] ints @0 | partials[1536] f32 @1024 | done @7168 | Ibf @8192
    int*   counts   = (int*)d_ws;
    float* partials = (float*)((char*)d_ws + 1024);
    unsigned int* done = (unsigned int*)((char*)d_ws + 7168);
    size_t need_bf16 = 8192 + (size_t)B * L * D * sizeof(unsigned short);

    if (ws_size >= need_bf16) {
        unsigned short* Ibf = (unsigned short*)((char*)d_ws + 8192);
        prep_kernel<<<B + 512, 256, 0, stream>>>(tmask, imask, I, counts, Ibf, done);
        sim_kernel_bf16<<<NWG, 256, 0, stream>>>(T, Ibf, counts, Iimp, Simp,
                                                 partials, done, (float*)d_out);
    } else {
        count_kernel<<<B, 256, 0, stream>>>(tmask, imask, counts);
        sim_kernel_f32<<<3 * B * 4, 256, 0, stream>>>(T, I, counts, Iimp, Simp, partials);
        loss_kernel<<<1, 384, 0, stream>>>(partials, (float*)d_out);
    }
}

// Round 7
// 145.317 us; speedup vs baseline: 1.0691x; 1.0691x over previous
//
#include <hip/hip_runtime.h>
#include <hip/hip_bf16.h>

#define B 128
#define N 1024
#define L 512
#define D 64

typedef float f32x4 __attribute__((ext_vector_type(4)));
typedef short bf16x8 __attribute__((ext_vector_type(8)));

// 8 fp32 -> 8 bf16 (RNE) via packed HW cvt
__device__ inline bf16x8 cvt8(float4 f0, float4 f1) {
    union { __hip_bfloat162 h2[4]; bf16x8 v; } u;
    u.h2[0] = __float22bfloat162_rn(make_float2(f0.x, f0.y));
    u.h2[1] = __float22bfloat162_rn(make_float2(f0.z, f0.w));
    u.h2[2] = __float22bfloat162_rn(make_float2(f1.x, f1.y));
    u.h2[3] = __float22bfloat162_rn(make_float2(f1.z, f1.w));
    return u.v;
}

// async global->LDS DMA (fallback path only)
__device__ __forceinline__ void gload16(const void* g, void* l) {
    __builtin_amdgcn_global_load_lds(
        (const __attribute__((address_space(1))) void*)g,
        (__attribute__((address_space(3))) void*)l, 16, 0, 0);
}

// ============================ bf16-workspace path ============================
// Fused pre-pass: blocks [0,B): mask counts; blocks [B,B+512): I fp32->bf16.
__global__ __launch_bounds__(256) void prep_kernel(
        const float* __restrict__ tmask, const float* __restrict__ imask,
        const float* __restrict__ I,
        int* __restrict__ counts, unsigned short* __restrict__ Ibf) {
    int blk = blockIdx.x, tid = threadIdx.x;
    if (blk < B) {
        int b = blk;
        int w = tid >> 6, lane = tid & 63;
        float ts = 0.f, is = 0.f;
        const float* tm = tmask + (size_t)b * N;
#pragma unroll
        for (int i = 0; i < N / 256; ++i) ts += tm[tid + i * 256];
        const float* im = imask + (size_t)b * L;
#pragma unroll
        for (int i = 0; i < L / 256; ++i) is += im[tid + i * 256];
        for (int off = 32; off; off >>= 1) {
            ts += __shfl_down(ts, off);
            is += __shfl_down(is, off);
        }
        __shared__ float red[8];
        if (lane == 0) { red[w] = ts; red[4 + w] = is; }
        __syncthreads();
        if (tid == 0) counts[b]     = (int)(red[0] + red[1] + red[2] + red[3] + 0.5f);
        if (tid == 1) counts[B + b] = (int)(red[4] + red[5] + red[6] + red[7] + 0.5f);
    } else {
        // 512 blocks x 256 thr x 4 chunks of 8 elems = 4,194,304 elems exactly
        int t = (blk - B) * 256 + tid;                 // 0..131071
#pragma unroll
        for (int j = 0; j < 4; ++j) {
            size_t ci = (size_t)t + (size_t)j * 131072;
            const float4* p = (const float4*)(I + ci * 8);
            *(bf16x8*)(Ibf + ci * 8) = cvt8(p[0], p[1]);
        }
    }
}

// grid = 1536 blocks (s,b,token-chunk) x 256 thr (4 waves x 64 tokens).
// STRUCTURAL change vs rounds 0-6: NO LDS staging at all. Ibf[b] is 64KB and
// L2/L3-resident (Common-mistake #7: don't stage what the cache serves).
// Each wave loads its MFMA B-fragments straight from global:
//   frag(rt,h) lane(q,c): Irow + (rt*16+c)*64 + h*32 + q*8   (16B dwordx4)
// Zero barriers in the chunk loop -> 4 blocks/CU x 4 fully-independent waves
// per block; TLP hides L2/HBM latency that the hand-rolled vmcnt pipeline
// (rounds 3-6) could not. Fused-tail + XCD swizzle of r6 reverted (the
// per-block threadfence+same-address atomic storm was the r6 regression).
__global__ __launch_bounds__(256, 4) void sim_kernel_bf16(
        const float* __restrict__ T, const unsigned short* __restrict__ Ibf,
        const int* __restrict__ counts,
        const int* __restrict__ Iimp, const int* __restrict__ Simp,
        float* __restrict__ partials) {
    int blk = blockIdx.x;          // 0..1535
    int chunk = blk & 3;
    int bs = blk >> 2;
    int b = bs & (B - 1);
    int s = bs >> 7;
    int Tb = b, Ib = b;
    if (s == 1) Tb = Simp[b];
    else if (s == 2) Ib = Iimp[b];

    int tid = threadIdx.x;
    int w = tid >> 6;
    int lane = tid & 63;
    int q = lane >> 4;
    int c = lane & 15;

    int ntok = counts[Tb];         // block-uniform
    int nreg = counts[B + Ib];

    int tok0 = chunk << 8;
    if (chunk != 0 && tok0 >= ntok) {      // ntok >= 256: chunk 0 never exits
        if (tid == 0) partials[blk] = 0.f;
        return;
    }

    __shared__ float red[4];

    // ---- A fragments: 4 token tiles x 2 K-halves (rows >= ntok masked at sum)
    int wt0 = tok0 + w * 64;
    bf16x8 afrag[4][2];
#pragma unroll
    for (int tt = 0; tt < 4; ++tt) {
        const float* trow = T + ((size_t)Tb * N + wt0 + tt * 16 + c) * D;
#pragma unroll
        for (int h = 0; h < 2; ++h) {
            const float4* p = (const float4*)(trow + h * 32 + q * 8);
            afrag[tt][h] = cvt8(p[0], p[1]);
        }
    }

    float mx[4][4];
#pragma unroll
    for (int tt = 0; tt < 4; ++tt)
#pragma unroll
        for (int i = 0; i < 4; ++i) mx[tt][i] = -3.0e38f;

    // ---- region-chunk loop: B-fragments direct from L2/L3 ----
    const unsigned short* Irow = Ibf + (size_t)Ib * L * D + q * 8;
    int nchunks = (nreg + 63) >> 6;              // 2..8 (nreg >= 128)
    int nregm1 = nreg - 1;

#pragma unroll 2
    for (int k = 0; k < nchunks; ++k) {
        int rbase = (k << 6) + c;
#pragma unroll
        for (int rt = 0; rt < 4; ++rt) {
            int r = rbase + rt * 16;
            if (r > nregm1) r = nregm1;          // duplicate valid row: max-neutral
            const unsigned short* p = Irow + (size_t)r * D;
            bf16x8 b0 = *(const bf16x8*)(p);         // k-elems q*8 .. +7
            bf16x8 b1 = *(const bf16x8*)(p + 32);    // k-elems 32+q*8 .. +7
#pragma unroll
            for (int tt = 0; tt < 4; ++tt) {
                f32x4 acc = {0.f, 0.f, 0.f, 0.f};
                acc = __builtin_amdgcn_mfma_f32_16x16x32_bf16(afrag[tt][0], b0, acc, 0, 0, 0);
                acc = __builtin_amdgcn_mfma_f32_16x16x32_bf16(afrag[tt][1], b1, acc, 0, 0, 0);
#pragma unroll
                for (int i = 0; i < 4; ++i) mx[tt][i] = fmaxf(mx[tt][i], acc[i]);
            }
        }
    }

    // ---- cross-lane max over 16 region-cols ----
#pragma unroll
    for (int m = 1; m < 16; m <<= 1) {
#pragma unroll
        for (int tt = 0; tt < 4; ++tt)
#pragma unroll
            for (int i = 0; i < 4; ++i)
                mx[tt][i] = fmaxf(mx[tt][i], __shfl_xor(mx[tt][i], m));
    }

    // ---- masked token sum (C layout: row = q*4 + i) ----
    float bsum = 0.f;
    if (c == 0) {
#pragma unroll
        for (int tt = 0; tt < 4; ++tt)
#pragma unroll
            for (int i = 0; i < 4; ++i) {
                int row = wt0 + tt * 16 + q * 4 + i;
                if (row < ntok) bsum += mx[tt][i];
            }
    }
    for (int off = 32; off; off >>= 1) bsum += __shfl_down(bsum, off);
    if (lane == 0) red[w] = bsum;
    __syncthreads();
    if (tid == 0)
        partials[blk] = (red[0] + red[1] + red[2] + red[3]) / (float)ntok;
}

// ===================== fallback path (tiny workspace, r3) =====================
__global__ __launch_bounds__(256) void count_kernel(
        const float* __restrict__ tmask, const float* __restrict__ imask,
        int* __restrict__ counts) {
    int b = blockIdx.x, tid = threadIdx.x;
    int w = tid >> 6, lane = tid & 63;
    float ts = 0.f, is = 0.f;
    const float* tm = tmask + (size_t)b * N;
#pragma unroll
    for (int i = 0; i < N / 256; ++i) ts += tm[tid + i * 256];
    const float* im = imask + (size_t)b * L;
#pragma unroll
    for (int i = 0; i < L / 256; ++i) is += im[tid + i * 256];
    for (int off = 32; off; off >>= 1) {
        ts += __shfl_down(ts, off);
        is += __shfl_down(is, off);
    }
    __shared__ float red[8];
    if (lane == 0) { red[w] = ts; red[4 + w] = is; }
    __syncthreads();
    if (tid == 0) counts[b]     = (int)(red[0] + red[1] + red[2] + red[3] + 0.5f);
    if (tid == 1) counts[B + b] = (int)(red[4] + red[5] + red[6] + red[7] + 0.5f);
}

// verbatim round-3 sim kernel (passed): fp32 DMA staging, 3x16KB LDS
__global__ __launch_bounds__(256, 3) void sim_kernel_f32(
        const float* __restrict__ T, const float* __restrict__ I,
        const int* __restrict__ counts,
        const int* __restrict__ Iimp, const int* __restrict__ Simp,
        float* __restrict__ partials) {
    int blk = blockIdx.x;
    int chunk = blk & 3;
    int bs = blk >> 2;
    int b = bs & (B - 1);
    int s = bs >> 7;
    int Tb = b, Ib = b;
    if (s == 1) Tb = Simp[b];
    else if (s == 2) Ib = Iimp[b];

    int tid = threadIdx.x;
    int w = tid >> 6;
    int lane = tid & 63;
    int q = lane >> 4;
    int c = lane & 15;

    int ntok = counts[Tb];
    int nreg = counts[B + Ib];

    int tok0 = chunk << 8;
    if (chunk != 0 && tok0 >= ntok) {
        if (tid == 0) partials[blk] = 0.f;
        return;
    }

    __shared__ float ldsI[3][4096];
    __shared__ float red[4];

    int wt0 = tok0 + w * 64;
    bf16x8 afrag[4][2];
#pragma unroll
    for (int tt = 0; tt < 4; ++tt) {
        const float* trow = T + ((size_t)Tb * N + wt0 + tt * 16 + c) * D;
#pragma unroll
        for (int h = 0; h < 2; ++h) {
            const float4* p = (const float4*)(trow + h * 32 + q * 8);
            afrag[tt][h] = cvt8(p[0], p[1]);
        }
    }

    float mx[4][4];
#pragma unroll
    for (int tt = 0; tt < 4; ++tt)
#pragma unroll
        for (int i = 0; i < 4; ++i) mx[tt][i] = -3.0e38f;

    int rloc[4], foff[4];
#pragma unroll
    for (int j = 0; j < 4; ++j) {
        int ci = tid + j * 256;
        int fh = ci >> 7, idx = ci & 127, half = idx >> 6, ln2 = idx & 63;
        rloc[j] = (fh >> 1) * 16 + (ln2 & 15);
        foff[j] = (fh & 1) * 32 + (ln2 >> 4) * 8 + half * 4;
    }
    const float* Ibase = I + (size_t)Ib * L * D;
    int nchunks = (nreg + 63) >> 6;
    int nregm1 = nreg - 1;

    auto stage = [&](int k) {
        float* buf = &ldsI[k % 3][0];
        int rbase = k << 6;
#pragma unroll
        for (int j = 0; j < 4; ++j) {
            int r = rbase + rloc[j];
            if (r > nregm1) r = nregm1;
            gload16(Ibase + (size_t)r * D + foff[j], buf + (tid + j * 256) * 4);
        }
    };

    asm volatile("s_waitcnt vmcnt(0)" ::: "memory");
    stage(0);
    stage(1);
    asm volatile("s_waitcnt vmcnt(4)" ::: "memory");
    __builtin_amdgcn_s_barrier();

    for (int k = 0; k < nchunks; ++k) {
        if (k + 2 < nchunks) stage(k + 2);

        const char* base = (const char*)&ldsI[k % 3][0] + (size_t)lane * 16;
#pragma unroll
        for (int rt = 0; rt < 4; ++rt) {
            float4 e0 = *(const float4*)(base + (rt * 2 + 0) * 2048);
            float4 e1 = *(const float4*)(base + (rt * 2 + 0) * 2048 + 1024);
            float4 e2 = *(const float4*)(base + (rt * 2 + 1) * 2048);
            float4 e3 = *(const float4*)(base + (rt * 2 + 1) * 2048 + 1024);
            bf16x8 b0 = cvt8(e0, e1);
            bf16x8 b1 = cvt8(e2, e3);
#pragma unroll
            for (int tt = 0; tt < 4; ++tt) {
                f32x4 acc = {0.f, 0.f, 0.f, 0.f};
                acc = __builtin_amdgcn_mfma_f32_16x16x32_bf16(afrag[tt][0], b0, acc, 0, 0, 0);
                acc = __builtin_amdgcn_mfma_f32_16x16x32_bf16(afrag[tt][1], b1, acc, 0, 0, 0);
#pragma unroll
                for (int i = 0; i < 4; ++i) mx[tt][i] = fmaxf(mx[tt][i], acc[i]);
            }
        }

        if (k + 1 < nchunks) {
            if (k + 2 < nchunks)
                asm volatile("s_waitcnt vmcnt(4) lgkmcnt(0)" ::: "memory");
            else
                asm volatile("s_waitcnt vmcnt(0) lgkmcnt(0)" ::: "memory");
            __builtin_amdgcn_s_barrier();
        }
    }

#pragma unroll
    for (int m = 1; m < 16; m <<= 1) {
#pragma unroll
        for (int tt = 0; tt < 4; ++tt)
#pragma unroll
            for (int i = 0; i < 4; ++i)
                mx[tt][i] = fmaxf(mx[tt][i], __shfl_xor(mx[tt][i], m));
    }

    float bsum = 0.f;
    if (c == 0) {
#pragma unroll
        for (int tt = 0; tt < 4; ++tt)
#pragma unroll
            for (int i = 0; i < 4; ++i) {
                int row = wt0 + tt * 16 + q * 4 + i;
                if (row < ntok) bsum += mx[tt][i];
            }
    }
    for (int off = 32; off; off >>= 1) bsum += __shfl_down(bsum, off);
    if (lane == 0) red[w] = bsum;
    __syncthreads();
    if (tid == 0)
        partials[blk] = (red[0] + red[1] + red[2] + red[3]) / (float)ntok;
}

// 1 block x 384 threads: fold 1536 partials -> 384 sims -> hinge -> loss
__global__ void loss_kernel(const float* __restrict__ partials,
                            float* __restrict__ out) {
    int tid = threadIdx.x;  // 0..383
    __shared__ float simsL[384];
    __shared__ float w6[6];
    const float4* p4 = (const float4*)partials;
    float4 v = p4[tid];
    simsL[tid] = v.x + v.y + v.z + v.w;
    __syncthreads();
    float per = 0.f;
    if (tid < B) {
        float anc  = simsL[tid];
        float simp = simsL[B + tid];
        float iimp = simsL[2 * B + tid];
        per = fmaxf(1.f + iimp - anc, 0.f) + fmaxf(1.f + simp - anc, 0.f);
    }
    for (int off = 32; off; off >>= 1) per += __shfl_down(per, off);
    if ((tid & 63) == 0) w6[tid >> 6] = per;
    __syncthreads();
    if (tid == 0)
        out[0] = (w6[0] + w6[1] + w6[2] + w6[3] + w6[4] + w6[5]) / (float)B;
}

extern "C" void kernel_launch(void* const* d_in, const int* in_sizes, int n_in,
                              void* d_out, int out_size, void* d_ws, size_t ws_size,
                              hipStream_t stream) {
    const float* T     = (const float*)d_in[0];
    const float* I     = (const float*)d_in[1];
    const float* tmask = (const float*)d_in[2];
    const float* imask = (const float*)d_in[3];
    const int*   Iimp  = (const int*)d_in[4];
    const int*   Simp  = (const int*)d_in[5];
    // ws: counts[256] ints @0 | partials[1536] f32 @1024 | Ibf bf16 @8192
    int*   counts   = (int*)d_ws;
    float* partials = (float*)((char*)d_ws + 1024);
    size_t need_bf16 = 8192 + (size_t)B * L * D * sizeof(unsigned short);

    if (ws_size >= need_bf16) {
        unsigned short* Ibf = (unsigned short*)((char*)d_ws + 8192);
        prep_kernel<<<B + 512, 256, 0, stream>>>(tmask, imask, I, counts, Ibf);
        sim_kernel_bf16<<<3 * B * 4, 256, 0, stream>>>(T, Ibf, counts, Iimp, Simp, partials);
    } else {
        count_kernel<<<B, 256, 0, stream>>>(tmask, imask, counts);
        sim_kernel_f32<<<3 * B * 4, 256, 0, stream>>>(T, I, counts, Iimp, Simp, partials);
    }
    loss_kernel<<<1, 384, 0, stream>>>(partials, (float*)d_out);
}

// Round 8
// 124.019 us; speedup vs baseline: 1.2528x; 1.1717x over previous
//
#include <hip/hip_runtime.h>
#include <hip/hip_bf16.h>

#define B 128
#define N 1024
#define L 512
#define D 64

typedef float f32x4 __attribute__((ext_vector_type(4)));
typedef short bf16x8 __attribute__((ext_vector_type(8)));

// 8 fp32 -> 8 bf16 (RNE) via packed HW cvt
__device__ inline bf16x8 cvt8(float4 f0, float4 f1) {
    union { __hip_bfloat162 h2[4]; bf16x8 v; } u;
    u.h2[0] = __float22bfloat162_rn(make_float2(f0.x, f0.y));
    u.h2[1] = __float22bfloat162_rn(make_float2(f0.z, f0.w));
    u.h2[2] = __float22bfloat162_rn(make_float2(f1.x, f1.y));
    u.h2[3] = __float22bfloat162_rn(make_float2(f1.z, f1.w));
    return u.v;
}

// async global->LDS DMA, 16B per lane; LDS dest must be linear base+lane*16
__device__ __forceinline__ void gload16(const void* g, void* l) {
    __builtin_amdgcn_global_load_lds(
        (const __attribute__((address_space(1))) void*)g,
        (__attribute__((address_space(3))) void*)l, 16, 0, 0);
}

// ============================ bf16-workspace path ============================
// Fused pre-pass: blocks [0,B): mask counts; blocks [B,B+512): I fp32->bf16.
// The bf16 conversion is what makes the whole-panel-in-LDS sim possible:
// 512 regions x 64 d x 2B = 64KB (fp32 would be 128KB > LDS).
__global__ __launch_bounds__(256) void prep_kernel(
        const float* __restrict__ tmask, const float* __restrict__ imask,
        const float* __restrict__ I,
        int* __restrict__ counts, unsigned short* __restrict__ Ibf) {
    int blk = blockIdx.x, tid = threadIdx.x;
    if (blk < B) {
        int b = blk;
        int w = tid >> 6, lane = tid & 63;
        float ts = 0.f, is = 0.f;
        const float* tm = tmask + (size_t)b * N;
#pragma unroll
        for (int i = 0; i < N / 256; ++i) ts += tm[tid + i * 256];
        const float* im = imask + (size_t)b * L;
#pragma unroll
        for (int i = 0; i < L / 256; ++i) is += im[tid + i * 256];
        for (int off = 32; off; off >>= 1) {
            ts += __shfl_down(ts, off);
            is += __shfl_down(is, off);
        }
        __shared__ float red[8];
        if (lane == 0) { red[w] = ts; red[4 + w] = is; }
        __syncthreads();
        if (tid == 0) counts[b]     = (int)(red[0] + red[1] + red[2] + red[3] + 0.5f);
        if (tid == 1) counts[B + b] = (int)(red[4] + red[5] + red[6] + red[7] + 0.5f);
    } else {
        // 512 blocks x 256 thr x 4 chunks of 8 elems = 4,194,304 elems exactly
        int t = (blk - B) * 256 + tid;                 // 0..131071
#pragma unroll
        for (int j = 0; j < 4; ++j) {
            size_t ci = (size_t)t + (size_t)j * 131072;
            const float4* p = (const float4*)(I + ci * 8);
            *(bf16x8*)(Ibf + ci * 8) = cvt8(p[0], p[1]);
        }
    }
}

// grid = 1536 blocks (s,b,token-chunk) x 256 thr (4 waves x 64 tokens).
// SINGLE-STAGE design (vs r5's per-chunk 3-buffer pipeline and r7's no-LDS):
// the whole Ibf[b] panel (nreg<=512 rows -> <=64KB bf16) is DMA'd to LDS in
// ONE burst; afrag T-loads issue behind it; ONE vmcnt(0)+barrier; then the
// region loop is pure ds_read_b128+MFMA with ZERO barriers/waits. This
// collapses the per-block serial chain (r0-r7: 2-8 latency-gated chunk steps)
// into one latency exposure + unbroken compute. LDS 64KB -> 2 blocks/CU.
// Fragment layout per chunk k (4096 shorts at k*4096), 16B chunk ci in
// [0,512): g=ci>>6 (=rt*2+h), ln=ci&63: region (g>>1)*16+(ln&15),
// elems (g&1)*32+(ln>>4)*8 .. +8. Conflict-free ds_read_b128 at
// base+lane*16 + (rt*2+h)*1024.
__global__ __launch_bounds__(256, 2) void sim_kernel_bf16(
        const float* __restrict__ T, const unsigned short* __restrict__ Ibf,
        const int* __restrict__ counts,
        const int* __restrict__ Iimp, const int* __restrict__ Simp,
        float* __restrict__ partials) {
    int blk = blockIdx.x;          // 0..1535
    int chunk = blk & 3;
    int bs = blk >> 2;
    int b = bs & (B - 1);
    int s = bs >> 7;
    int Tb = b, Ib = b;
    if (s == 1) Tb = Simp[b];
    else if (s == 2) Ib = Iimp[b];

    int tid = threadIdx.x;
    int w = tid >> 6;
    int lane = tid & 63;
    int q = lane >> 4;
    int c = lane & 15;

    int ntok = counts[Tb];         // block-uniform
    int nreg = counts[B + Ib];

    int tok0 = chunk << 8;
    if (chunk != 0 && tok0 >= ntok) {      // ntok >= 256: chunk 0 never exits
        if (tid == 0) partials[blk] = 0.f;
        return;
    }

    __shared__ unsigned short ldsI[512 * D];     // 64 KB: whole region panel
    __shared__ float red[4];

    // ---- staging decode: 2 x 16B DMA per thread per 64-region chunk ----
    int rloc[2], eoff[2];
#pragma unroll
    for (int j = 0; j < 2; ++j) {
        int ci = tid + j * 256;
        int g = ci >> 6, ln = ci & 63;
        rloc[j] = (g >> 1) * 16 + (ln & 15);
        eoff[j] = (g & 1) * 32 + (ln >> 4) * 8;
    }
    const unsigned short* Ibase = Ibf + (size_t)Ib * L * D;
    int nchunks = (nreg + 63) >> 6;              // 2..8 (nreg >= 128)
    int nregm1 = nreg - 1;

    // ---- issue ALL staging DMA up front (<=16 in flight per lane) ----
    for (int k = 0; k < nchunks; ++k) {
        unsigned short* buf = &ldsI[k * 4096];
        int rbase = k << 6;
#pragma unroll
        for (int j = 0; j < 2; ++j) {
            int r = rbase + rloc[j];
            if (r > nregm1) r = nregm1;          // duplicate valid row: max-neutral
            gload16(Ibase + (size_t)r * D + eoff[j], buf + (size_t)(tid + j * 256) * 8);
        }
    }

    // ---- A fragments issue behind the DMA burst (one shared drain below) ----
    int wt0 = tok0 + w * 64;
    bf16x8 afrag[4][2];
#pragma unroll
    for (int tt = 0; tt < 4; ++tt) {
        const float* trow = T + ((size_t)Tb * N + wt0 + tt * 16 + c) * D;
#pragma unroll
        for (int h = 0; h < 2; ++h) {
            const float4* p = (const float4*)(trow + h * 32 + q * 8);
            afrag[tt][h] = cvt8(p[0], p[1]);
        }
    }

    float mx[4][4];
#pragma unroll
    for (int tt = 0; tt < 4; ++tt)
#pragma unroll
        for (int i = 0; i < 4; ++i) mx[tt][i] = -3.0e38f;

    // ---- ONE drain + ONE barrier for the whole kernel ----
    asm volatile("s_waitcnt vmcnt(0)" ::: "memory");
    __builtin_amdgcn_s_barrier();

    // ---- pure-LDS compute: no barriers, no waits, 32 MFMA per chunk ----
#pragma unroll 2
    for (int k = 0; k < nchunks; ++k) {
        const char* base = (const char*)&ldsI[k * 4096] + (size_t)lane * 16;
#pragma unroll
        for (int rt = 0; rt < 4; ++rt) {
            bf16x8 b0 = *(const bf16x8*)(base + (rt * 2 + 0) * 1024);
            bf16x8 b1 = *(const bf16x8*)(base + (rt * 2 + 1) * 1024);
#pragma unroll
            for (int tt = 0; tt < 4; ++tt) {
                f32x4 acc = {0.f, 0.f, 0.f, 0.f};
                acc = __builtin_amdgcn_mfma_f32_16x16x32_bf16(afrag[tt][0], b0, acc, 0, 0, 0);
                acc = __builtin_amdgcn_mfma_f32_16x16x32_bf16(afrag[tt][1], b1, acc, 0, 0, 0);
#pragma unroll
                for (int i = 0; i < 4; ++i) mx[tt][i] = fmaxf(mx[tt][i], acc[i]);
            }
        }
    }

    // ---- cross-lane max over 16 region-cols ----
#pragma unroll
    for (int m = 1; m < 16; m <<= 1) {
#pragma unroll
        for (int tt = 0; tt < 4; ++tt)
#pragma unroll
            for (int i = 0; i < 4; ++i)
                mx[tt][i] = fmaxf(mx[tt][i], __shfl_xor(mx[tt][i], m));
    }

    // ---- masked token sum (C layout: row = q*4 + i) ----
    float bsum = 0.f;
    if (c == 0) {
#pragma unroll
        for (int tt = 0; tt < 4; ++tt)
#pragma unroll
            for (int i = 0; i < 4; ++i) {
                int row = wt0 + tt * 16 + q * 4 + i;
                if (row < ntok) bsum += mx[tt][i];
            }
    }
    for (int off = 32; off; off >>= 1) bsum += __shfl_down(bsum, off);
    if (lane == 0) red[w] = bsum;
    __syncthreads();
    if (tid == 0)
        partials[blk] = (red[0] + red[1] + red[2] + red[3]) / (float)ntok;
}

// ===================== fallback path (tiny workspace, r3) =====================
__global__ __launch_bounds__(256) void count_kernel(
        const float* __restrict__ tmask, const float* __restrict__ imask,
        int* __restrict__ counts) {
    int b = blockIdx.x, tid = threadIdx.x;
    int w = tid >> 6, lane = tid & 63;
    float ts = 0.f, is = 0.f;
    const float* tm = tmask + (size_t)b * N;
#pragma unroll
    for (int i = 0; i < N / 256; ++i) ts += tm[tid + i * 256];
    const float* im = imask + (size_t)b * L;
#pragma unroll
    for (int i = 0; i < L / 256; ++i) is += im[tid + i * 256];
    for (int off = 32; off; off >>= 1) {
        ts += __shfl_down(ts, off);
        is += __shfl_down(is, off);
    }
    __shared__ float red[8];
    if (lane == 0) { red[w] = ts; red[4 + w] = is; }
    __syncthreads();
    if (tid == 0) counts[b]     = (int)(red[0] + red[1] + red[2] + red[3] + 0.5f);
    if (tid == 1) counts[B + b] = (int)(red[4] + red[5] + red[6] + red[7] + 0.5f);
}

// verbatim round-3 sim kernel (passed): fp32 DMA staging, 3x16KB LDS
__global__ __launch_bounds__(256, 3) void sim_kernel_f32(
        const float* __restrict__ T, const float* __restrict__ I,
        const int* __restrict__ counts,
        const int* __restrict__ Iimp, const int* __restrict__ Simp,
        float* __restrict__ partials) {
    int blk = blockIdx.x;
    int chunk = blk & 3;
    int bs = blk >> 2;
    int b = bs & (B - 1);
    int s = bs >> 7;
    int Tb = b, Ib = b;
    if (s == 1) Tb = Simp[b];
    else if (s == 2) Ib = Iimp[b];

    int tid = threadIdx.x;
    int w = tid >> 6;
    int lane = tid & 63;
    int q = lane >> 4;
    int c = lane & 15;

    int ntok = counts[Tb];
    int nreg = counts[B + Ib];

    int tok0 = chunk << 8;
    if (chunk != 0 && tok0 >= ntok) {
        if (tid == 0) partials[blk] = 0.f;
        return;
    }

    __shared__ float ldsI[3][4096];
    __shared__ float red[4];

    int wt0 = tok0 + w * 64;
    bf16x8 afrag[4][2];
#pragma unroll
    for (int tt = 0; tt < 4; ++tt) {
        const float* trow = T + ((size_t)Tb * N + wt0 + tt * 16 + c) * D;
#pragma unroll
        for (int h = 0; h < 2; ++h) {
            const float4* p = (const float4*)(trow + h * 32 + q * 8);
            afrag[tt][h] = cvt8(p[0], p[1]);
        }
    }

    float mx[4][4];
#pragma unroll
    for (int tt = 0; tt < 4; ++tt)
#pragma unroll
        for (int i = 0; i < 4; ++i) mx[tt][i] = -3.0e38f;

    int rloc[4], foff[4];
#pragma unroll
    for (int j = 0; j < 4; ++j) {
        int ci = tid + j * 256;
        int fh = ci >> 7, idx = ci & 127, half = idx >> 6, ln2 = idx & 63;
        rloc[j] = (fh >> 1) * 16 + (ln2 & 15);
        foff[j] = (fh & 1) * 32 + (ln2 >> 4) * 8 + half * 4;
    }
    const float* Ibase = I + (size_t)Ib * L * D;
    int nchunks = (nreg + 63) >> 6;
    int nregm1 = nreg - 1;

    auto stage = [&](int k) {
        float* buf = &ldsI[k % 3][0];
        int rbase = k << 6;
#pragma unroll
        for (int j = 0; j < 4; ++j) {
            int r = rbase + rloc[j];
            if (r > nregm1) r = nregm1;
            gload16(Ibase + (size_t)r * D + foff[j], buf + (tid + j * 256) * 4);
        }
    };

    asm volatile("s_waitcnt vmcnt(0)" ::: "memory");
    stage(0);
    stage(1);
    asm volatile("s_waitcnt vmcnt(4)" ::: "memory");
    __builtin_amdgcn_s_barrier();

    for (int k = 0; k < nchunks; ++k) {
        if (k + 2 < nchunks) stage(k + 2);

        const char* base = (const char*)&ldsI[k % 3][0] + (size_t)lane * 16;
#pragma unroll
        for (int rt = 0; rt < 4; ++rt) {
            float4 e0 = *(const float4*)(base + (rt * 2 + 0) * 2048);
            float4 e1 = *(const float4*)(base + (rt * 2 + 0) * 2048 + 1024);
            float4 e2 = *(const float4*)(base + (rt * 2 + 1) * 2048);
            float4 e3 = *(const float4*)(base + (rt * 2 + 1) * 2048 + 1024);
            bf16x8 b0 = cvt8(e0, e1);
            bf16x8 b1 = cvt8(e2, e3);
#pragma unroll
            for (int tt = 0; tt < 4; ++tt) {
                f32x4 acc = {0.f, 0.f, 0.f, 0.f};
                acc = __builtin_amdgcn_mfma_f32_16x16x32_bf16(afrag[tt][0], b0, acc, 0, 0, 0);
                acc = __builtin_amdgcn_mfma_f32_16x16x32_bf16(afrag[tt][1], b1, acc, 0, 0, 0);
#pragma unroll
                for (int i = 0; i < 4; ++i) mx[tt][i] = fmaxf(mx[tt][i], acc[i]);
            }
        }

        if (k + 1 < nchunks) {
            if (k + 2 < nchunks)
                asm volatile("s_waitcnt vmcnt(4) lgkmcnt(0)" ::: "memory");
            else
                asm volatile("s_waitcnt vmcnt(0) lgkmcnt(0)" ::: "memory");
            __builtin_amdgcn_s_barrier();
        }
    }

#pragma unroll
    for (int m = 1; m < 16; m <<= 1) {
#pragma unroll
        for (int tt = 0; tt < 4; ++tt)
#pragma unroll
            for (int i = 0; i < 4; ++i)
                mx[tt][i] = fmaxf(mx[tt][i], __shfl_xor(mx[tt][i], m));
    }

    float bsum = 0.f;
    if (c == 0) {
#pragma unroll
        for (int tt = 0; tt < 4; ++tt)
#pragma unroll
            for (int i = 0; i < 4; ++i) {
                int row = wt0 + tt * 16 + q * 4 + i;
                if (row < ntok) bsum += mx[tt][i];
            }
    }
    for (int off = 32; off; off >>= 1) bsum += __shfl_down(bsum, off);
    if (lane == 0) red[w] = bsum;
    __syncthreads();
    if (tid == 0)
        partials[blk] = (red[0] + red[1] + red[2] + red[3]) / (float)ntok;
}

// 1 block x 384 threads: fold 1536 partials -> 384 sims -> hinge -> loss
__global__ void loss_kernel(const float* __restrict__ partials,
                            float* __restrict__ out) {
    int tid = threadIdx.x;  // 0..383
    __shared__ float simsL[384];
    __shared__ float w6[6];
    const float4* p4 = (const float4*)partials;
    float4 v = p4[tid];
    simsL[tid] = v.x + v.y + v.z + v.w;
    __syncthreads();
    float per = 0.f;
    if (tid < B) {
        float anc  = simsL[tid];
        float simp = simsL[B + tid];
        float iimp = simsL[2 * B + tid];
        per = fmaxf(1.f + iimp - anc, 0.f) + fmaxf(1.f + simp - anc, 0.f);
    }
    for (int off = 32; off; off >>= 1) per += __shfl_down(per, off);
    if ((tid & 63) == 0) w6[tid >> 6] = per;
    __syncthreads();
    if (tid == 0)
        out[0] = (w6[0] + w6[1] + w6[2] + w6[3] + w6[4] + w6[5]) / (float)B;
}

extern "C" void kernel_launch(void* const* d_in, const int* in_sizes, int n_in,
                              void* d_out, int out_size, void* d_ws, size_t ws_size,
                              hipStream_t stream) {
    const float* T     = (const float*)d_in[0];
    const float* I     = (const float*)d_in[1];
    const float* tmask = (const float*)d_in[2];
    const float* imask = (const float*)d_in[3];
    const int*   Iimp  = (const int*)d_in[4];
    const int*   Simp  = (const int*)d_in[5];
    // ws: counts[256] ints @0 | partials[1536] f32 @1024 | Ibf bf16 @8192
    int*   counts   = (int*)d_ws;
    float* partials = (float*)((char*)d_ws + 1024);
    size_t need_bf16 = 8192 + (size_t)B * L * D * sizeof(unsigned short);

    if (ws_size >= need_bf16) {
        unsigned short* Ibf = (unsigned short*)((char*)d_ws + 8192);
        prep_kernel<<<B + 512, 256, 0, stream>>>(tmask, imask, I, counts, Ibf);
        sim_kernel_bf16<<<3 * B * 4, 256, 0, stream>>>(T, Ibf, counts, Iimp, Simp, partials);
    } else {
        count_kernel<<<B, 256, 0, stream>>>(tmask, imask, counts);
        sim_kernel_f32<<<3 * B * 4, 256, 0, stream>>>(T, I, counts, Iimp, Simp, partials);
    }
    loss_kernel<<<1, 384, 0, stream>>>(partials, (float*)d_out);
}

// Round 9
// 121.634 us; speedup vs baseline: 1.2773x; 1.0196x over previous
//
#include <hip/hip_runtime.h>
#include <hip/hip_bf16.h>

#define B 128
#define N 1024
#define L 512
#define D 64

typedef float f32x4 __attribute__((ext_vector_type(4)));
typedef short bf16x8 __attribute__((ext_vector_type(8)));

// 8 fp32 -> 8 bf16 (RNE) via packed HW cvt
__device__ inline bf16x8 cvt8(float4 f0, float4 f1) {
    union { __hip_bfloat162 h2[4]; bf16x8 v; } u;
    u.h2[0] = __float22bfloat162_rn(make_float2(f0.x, f0.y));
    u.h2[1] = __float22bfloat162_rn(make_float2(f0.z, f0.w));
    u.h2[2] = __float22bfloat162_rn(make_float2(f1.x, f1.y));
    u.h2[3] = __float22bfloat162_rn(make_float2(f1.z, f1.w));
    return u.v;
}

// async global->LDS DMA, 16B per lane; LDS dest must be linear base+lane*16
__device__ __forceinline__ void gload16(const void* g, void* l) {
    __builtin_amdgcn_global_load_lds(
        (const __attribute__((address_space(1))) void*)g,
        (__attribute__((address_space(3))) void*)l, 16, 0, 0);
}

// ============================ bf16-workspace path ============================
// Fused pre-pass: blocks [0,B): mask counts; blocks [B,B+512): I fp32->bf16.
// The bf16 conversion is what makes the whole-panel-in-LDS sim possible:
// 512 regions x 64 d x 2B = 64KB (fp32 would be 128KB > LDS).
__global__ __launch_bounds__(256) void prep_kernel(
        const float* __restrict__ tmask, const float* __restrict__ imask,
        const float* __restrict__ I,
        int* __restrict__ counts, unsigned short* __restrict__ Ibf) {
    int blk = blockIdx.x, tid = threadIdx.x;
    if (blk < B) {
        int b = blk;
        int w = tid >> 6, lane = tid & 63;
        float ts = 0.f, is = 0.f;
        const float* tm = tmask + (size_t)b * N;
#pragma unroll
        for (int i = 0; i < N / 256; ++i) ts += tm[tid + i * 256];
        const float* im = imask + (size_t)b * L;
#pragma unroll
        for (int i = 0; i < L / 256; ++i) is += im[tid + i * 256];
        for (int off = 32; off; off >>= 1) {
            ts += __shfl_down(ts, off);
            is += __shfl_down(is, off);
        }
        __shared__ float red[8];
        if (lane == 0) { red[w] = ts; red[4 + w] = is; }
        __syncthreads();
        if (tid == 0) counts[b]     = (int)(red[0] + red[1] + red[2] + red[3] + 0.5f);
        if (tid == 1) counts[B + b] = (int)(red[4] + red[5] + red[6] + red[7] + 0.5f);
    } else {
        // 512 blocks x 256 thr x 4 chunks of 8 elems = 4,194,304 elems exactly
        int t = (blk - B) * 256 + tid;                 // 0..131071
#pragma unroll
        for (int j = 0; j < 4; ++j) {
            size_t ci = (size_t)t + (size_t)j * 131072;
            const float4* p = (const float4*)(I + ci * 8);
            *(bf16x8*)(Ibf + ci * 8) = cvt8(p[0], p[1]);
        }
    }
}

// grid = 384 blocks = (s,b) x 256 thr (4 waves x 64 tokens per chunk).
// vs r8 (1536 chunk-blocks, 3 residency rounds, panel staged 4x): ONE block
// per (s,b) stages the panel ONCE, then loops the 1-4 active token-chunks
// internally with ZERO barriers between them (LDS read-only after the single
// prologue barrier). 384 blocks <= 512 residency slots (64KB LDS -> 2/CU):
// the whole grid is co-resident -> one stage-drain latency exposure per
// (s,b), staging traffic /4, no tail rounds.
// Fragment layout per region-chunk k (4096 shorts at k*4096), 16B chunk ci in
// [0,512): g=ci>>6 (=rt*2+h), ln=ci&63: region (g>>1)*16+(ln&15),
// elems (g&1)*32+(ln>>4)*8 .. +8. Conflict-free ds_read_b128 at
// base+lane*16 + (rt*2+h)*1024.
__global__ __launch_bounds__(256, 2) void sim_kernel_bf16(
        const float* __restrict__ T, const unsigned short* __restrict__ Ibf,
        const int* __restrict__ counts,
        const int* __restrict__ Iimp, const int* __restrict__ Simp,
        float* __restrict__ sims) {
    int blk = blockIdx.x;          // 0..383 = s*128 + b
    int b = blk & (B - 1);
    int s = blk >> 7;
    int Tb = b, Ib = b;
    if (s == 1) Tb = Simp[b];
    else if (s == 2) Ib = Iimp[b];

    int tid = threadIdx.x;
    int w = tid >> 6;
    int lane = tid & 63;
    int q = lane >> 4;
    int c = lane & 15;

    int ntok = counts[Tb];         // block-uniform
    int nreg = counts[B + Ib];

    __shared__ unsigned short ldsI[512 * D];     // 64 KB: whole region panel
    __shared__ float red[4];

    // ---- staging decode: 2 x 16B DMA per thread per 64-region chunk ----
    int rloc[2], eoff[2];
#pragma unroll
    for (int j = 0; j < 2; ++j) {
        int ci = tid + j * 256;
        int g = ci >> 6, ln = ci & 63;
        rloc[j] = (g >> 1) * 16 + (ln & 15);
        eoff[j] = (g & 1) * 32 + (ln >> 4) * 8;
    }
    const unsigned short* Ibase = Ibf + (size_t)Ib * L * D;
    int nchunks = (nreg + 63) >> 6;              // 2..8 (nreg >= 128)
    int nregm1 = nreg - 1;

    // ---- issue ALL staging DMA up front (<=16 in flight per lane) ----
    for (int k = 0; k < nchunks; ++k) {
        unsigned short* buf = &ldsI[k * 4096];
        int rbase = k << 6;
#pragma unroll
        for (int j = 0; j < 2; ++j) {
            int r = rbase + rloc[j];
            if (r > nregm1) r = nregm1;          // duplicate valid row: max-neutral
            gload16(Ibase + (size_t)r * D + eoff[j], buf + (size_t)(tid + j * 256) * 8);
        }
    }

    int nTokC = (ntok + 255) >> 8;               // 1..4 active token chunks
    float asum = 0.f;

    for (int tc = 0; tc < nTokC; ++tc) {
        // ---- A fragments for this token chunk (rows >= ntok masked at sum) ----
        int wt0 = (tc << 8) + w * 64;
        bf16x8 afrag[4][2];
#pragma unroll
        for (int tt = 0; tt < 4; ++tt) {
            const float* trow = T + ((size_t)Tb * N + wt0 + tt * 16 + c) * D;
#pragma unroll
            for (int h = 0; h < 2; ++h) {
                const float4* p = (const float4*)(trow + h * 32 + q * 8);
                afrag[tt][h] = cvt8(p[0], p[1]);
            }
        }

        if (tc == 0) {
            // ONE drain + ONE barrier for the whole kernel (DMA + tc0 afrag)
            asm volatile("s_waitcnt vmcnt(0)" ::: "memory");
            __builtin_amdgcn_s_barrier();
        }

        float mx[4][4];
#pragma unroll
        for (int tt = 0; tt < 4; ++tt)
#pragma unroll
            for (int i = 0; i < 4; ++i) mx[tt][i] = -3.0e38f;

        // ---- pure-LDS region loop: no barriers, no waits, 32 MFMA/chunk ----
#pragma unroll 2
        for (int k = 0; k < nchunks; ++k) {
            const char* base = (const char*)&ldsI[k * 4096] + (size_t)lane * 16;
#pragma unroll
            for (int rt = 0; rt < 4; ++rt) {
                bf16x8 b0 = *(const bf16x8*)(base + (rt * 2 + 0) * 1024);
                bf16x8 b1 = *(const bf16x8*)(base + (rt * 2 + 1) * 1024);
#pragma unroll
                for (int tt = 0; tt < 4; ++tt) {
                    f32x4 acc = {0.f, 0.f, 0.f, 0.f};
                    acc = __builtin_amdgcn_mfma_f32_16x16x32_bf16(afrag[tt][0], b0, acc, 0, 0, 0);
                    acc = __builtin_amdgcn_mfma_f32_16x16x32_bf16(afrag[tt][1], b1, acc, 0, 0, 0);
#pragma unroll
                    for (int i = 0; i < 4; ++i) mx[tt][i] = fmaxf(mx[tt][i], acc[i]);
                }
            }
        }

        // ---- cross-lane max over 16 region-cols ----
#pragma unroll
        for (int m = 1; m < 16; m <<= 1) {
#pragma unroll
            for (int tt = 0; tt < 4; ++tt)
#pragma unroll
                for (int i = 0; i < 4; ++i)
                    mx[tt][i] = fmaxf(mx[tt][i], __shfl_xor(mx[tt][i], m));
        }

        // ---- masked token sum (C layout: row = q*4 + i), accumulate ----
        if (c == 0) {
#pragma unroll
            for (int tt = 0; tt < 4; ++tt)
#pragma unroll
                for (int i = 0; i < 4; ++i) {
                    int row = wt0 + tt * 16 + q * 4 + i;
                    if (row < ntok) asum += mx[tt][i];
                }
        }
    }

    // ---- single final reduction + direct sim write ----
    for (int off = 32; off; off >>= 1) asum += __shfl_down(asum, off);
    if (lane == 0) red[w] = asum;
    __syncthreads();
    if (tid == 0)
        sims[blk] = (red[0] + red[1] + red[2] + red[3]) / (float)ntok;
}

// 1 block x 384 threads: direct hinge over sims[384]
__global__ void loss_kernel_direct(const float* __restrict__ sims,
                                   float* __restrict__ out) {
    int tid = threadIdx.x;  // 0..383
    __shared__ float w6[6];
    float per = 0.f;
    if (tid < B) {
        float anc  = sims[tid];
        float simp = sims[B + tid];
        float iimp = sims[2 * B + tid];
        per = fmaxf(1.f + iimp - anc, 0.f) + fmaxf(1.f + simp - anc, 0.f);
    }
    for (int off = 32; off; off >>= 1) per += __shfl_down(per, off);
    if ((tid & 63) == 0) w6[tid >> 6] = per;
    __syncthreads();
    if (tid == 0)
        out[0] = (w6[0] + w6[1] + w6[2] + w6[3] + w6[4] + w6[5]) / (float)B;
}

// ===================== fallback path (tiny workspace, r3) =====================
__global__ __launch_bounds__(256) void count_kernel(
        const float* __restrict__ tmask, const float* __restrict__ imask,
        int* __restrict__ counts) {
    int b = blockIdx.x, tid = threadIdx.x;
    int w = tid >> 6, lane = tid & 63;
    float ts = 0.f, is = 0.f;
    const float* tm = tmask + (size_t)b * N;
#pragma unroll
    for (int i = 0; i < N / 256; ++i) ts += tm[tid + i * 256];
    const float* im = imask + (size_t)b * L;
#pragma unroll
    for (int i = 0; i < L / 256; ++i) is += im[tid + i * 256];
    for (int off = 32; off; off >>= 1) {
        ts += __shfl_down(ts, off);
        is += __shfl_down(is, off);
    }
    __shared__ float red[8];
    if (lane == 0) { red[w] = ts; red[4 + w] = is; }
    __syncthreads();
    if (tid == 0) counts[b]     = (int)(red[0] + red[1] + red[2] + red[3] + 0.5f);
    if (tid == 1) counts[B + b] = (int)(red[4] + red[5] + red[6] + red[7] + 0.5f);
}

// verbatim round-3 sim kernel (passed): fp32 DMA staging, 3x16KB LDS
__global__ __launch_bounds__(256, 3) void sim_kernel_f32(
        const float* __restrict__ T, const float* __restrict__ I,
        const int* __restrict__ counts,
        const int* __restrict__ Iimp, const int* __restrict__ Simp,
        float* __restrict__ partials) {
    int blk = blockIdx.x;
    int chunk = blk & 3;
    int bs = blk >> 2;
    int b = bs & (B - 1);
    int s = bs >> 7;
    int Tb = b, Ib = b;
    if (s == 1) Tb = Simp[b];
    else if (s == 2) Ib = Iimp[b];

    int tid = threadIdx.x;
    int w = tid >> 6;
    int lane = tid & 63;
    int q = lane >> 4;
    int c = lane & 15;

    int ntok = counts[Tb];
    int nreg = counts[B + Ib];

    int tok0 = chunk << 8;
    if (chunk != 0 && tok0 >= ntok) {
        if (tid == 0) partials[blk] = 0.f;
        return;
    }

    __shared__ float ldsI[3][4096];
    __shared__ float red[4];

    int wt0 = tok0 + w * 64;
    bf16x8 afrag[4][2];
#pragma unroll
    for (int tt = 0; tt < 4; ++tt) {
        const float* trow = T + ((size_t)Tb * N + wt0 + tt * 16 + c) * D;
#pragma unroll
        for (int h = 0; h < 2; ++h) {
            const float4* p = (const float4*)(trow + h * 32 + q * 8);
            afrag[tt][h] = cvt8(p[0], p[1]);
        }
    }

    float mx[4][4];
#pragma unroll
    for (int tt = 0; tt < 4; ++tt)
#pragma unroll
        for (int i = 0; i < 4; ++i) mx[tt][i] = -3.0e38f;

    int rloc[4], foff[4];
#pragma unroll
    for (int j = 0; j < 4; ++j) {
        int ci = tid + j * 256;
        int fh = ci >> 7, idx = ci & 127, half = idx >> 6, ln2 = idx & 63;
        rloc[j] = (fh >> 1) * 16 + (ln2 & 15);
        foff[j] = (fh & 1) * 32 + (ln2 >> 4) * 8 + half * 4;
    }
    const float* Ibase = I + (size_t)Ib * L * D;
    int nchunks = (nreg + 63) >> 6;
    int nregm1 = nreg - 1;

    auto stage = [&](int k) {
        float* buf = &ldsI[k % 3][0];
        int rbase = k << 6;
#pragma unroll
        for (int j = 0; j < 4; ++j) {
            int r = rbase + rloc[j];
            if (r > nregm1) r = nregm1;
            gload16(Ibase + (size_t)r * D + foff[j], buf + (tid + j * 256) * 4);
        }
    };

    asm volatile("s_waitcnt vmcnt(0)" ::: "memory");
    stage(0);
    stage(1);
    asm volatile("s_waitcnt vmcnt(4)" ::: "memory");
    __builtin_amdgcn_s_barrier();

    for (int k = 0; k < nchunks; ++k) {
        if (k + 2 < nchunks) stage(k + 2);

        const char* base = (const char*)&ldsI[k % 3][0] + (size_t)lane * 16;
#pragma unroll
        for (int rt = 0; rt < 4; ++rt) {
            float4 e0 = *(const float4*)(base + (rt * 2 + 0) * 2048);
            float4 e1 = *(const float4*)(base + (rt * 2 + 0) * 2048 + 1024);
            float4 e2 = *(const float4*)(base + (rt * 2 + 1) * 2048);
            float4 e3 = *(const float4*)(base + (rt * 2 + 1) * 2048 + 1024);
            bf16x8 b0 = cvt8(e0, e1);
            bf16x8 b1 = cvt8(e2, e3);
#pragma unroll
            for (int tt = 0; tt < 4; ++tt) {
                f32x4 acc = {0.f, 0.f, 0.f, 0.f};
                acc = __builtin_amdgcn_mfma_f32_16x16x32_bf16(afrag[tt][0], b0, acc, 0, 0, 0);
                acc = __builtin_amdgcn_mfma_f32_16x16x32_bf16(afrag[tt][1], b1, acc, 0, 0, 0);
#pragma unroll
                for (int i = 0; i < 4; ++i) mx[tt][i] = fmaxf(mx[tt][i], acc[i]);
            }
        }

        if (k + 1 < nchunks) {
            if (k + 2 < nchunks)
                asm volatile("s_waitcnt vmcnt(4) lgkmcnt(0)" ::: "memory");
            else
                asm volatile("s_waitcnt vmcnt(0) lgkmcnt(0)" ::: "memory");
            __builtin_amdgcn_s_barrier();
        }
    }

#pragma unroll
    for (int m = 1; m < 16; m <<= 1) {
#pragma unroll
        for (int tt = 0; tt < 4; ++tt)
#pragma unroll
            for (int i = 0; i < 4; ++i)
                mx[tt][i] = fmaxf(mx[tt][i], __shfl_xor(mx[tt][i], m));
    }

    float bsum = 0.f;
    if (c == 0) {
#pragma unroll
        for (int tt = 0; tt < 4; ++tt)
#pragma unroll
            for (int i = 0; i < 4; ++i) {
                int row = wt0 + tt * 16 + q * 4 + i;
                if (row < ntok) bsum += mx[tt][i];
            }
    }
    for (int off = 32; off; off >>= 1) bsum += __shfl_down(bsum, off);
    if (lane == 0) red[w] = bsum;
    __syncthreads();
    if (tid == 0)
        partials[blk] = (red[0] + red[1] + red[2] + red[3]) / (float)ntok;
}

// 1 block x 384 threads: fold 1536 partials -> 384 sims -> hinge -> loss
__global__ void loss_kernel(const float* __restrict__ partials,
                            float* __restrict__ out) {
    int tid = threadIdx.x;  // 0..383
    __shared__ float simsL[384];
    __shared__ float w6[6];
    const float4* p4 = (const float4*)partials;
    float4 v = p4[tid];
    simsL[tid] = v.x + v.y + v.z + v.w;
    __syncthreads();
    float per = 0.f;
    if (tid < B) {
        float anc  = simsL[tid];
        float simp = simsL[B + tid];
        float iimp = simsL[2 * B + tid];
        per = fmaxf(1.f + iimp - anc, 0.f) + fmaxf(1.f + simp - anc, 0.f);
    }
    for (int off = 32; off; off >>= 1) per += __shfl_down(per, off);
    if ((tid & 63) == 0) w6[tid >> 6] = per;
    __syncthreads();
    if (tid == 0)
        out[0] = (w6[0] + w6[1] + w6[2] + w6[3] + w6[4] + w6[5]) / (float)B;
}

extern "C" void kernel_launch(void* const* d_in, const int* in_sizes, int n_in,
                              void* d_out, int out_size, void* d_ws, size_t ws_size,
                              hipStream_t stream) {
    const float* T     = (const float*)d_in[0];
    const float* I     = (const float*)d_in[1];
    const float* tmask = (const float*)d_in[2];
    const float* imask = (const float*)d_in[3];
    const int*   Iimp  = (const int*)d_in[4];
    const int*   Simp  = (const int*)d_in[5];
    // ws: counts[256] ints @0 | sims/partials f32 @1024 | Ibf bf16 @8192
    int*   counts   = (int*)d_ws;
    float* partials = (float*)((char*)d_ws + 1024);
    size_t need_bf16 = 8192 + (size_t)B * L * D * sizeof(unsigned short);

    if (ws_size >= need_bf16) {
        unsigned short* Ibf = (unsigned short*)((char*)d_ws + 8192);
        prep_kernel<<<B + 512, 256, 0, stream>>>(tmask, imask, I, counts, Ibf);
        sim_kernel_bf16<<<3 * B, 256, 0, stream>>>(T, Ibf, counts, Iimp, Simp, partials);
        loss_kernel_direct<<<1, 384, 0, stream>>>(partials, (float*)d_out);
    } else {
        count_kernel<<<B, 256, 0, stream>>>(tmask, imask, counts);
        sim_kernel_f32<<<3 * B * 4, 256, 0, stream>>>(T, I, counts, Iimp, Simp, partials);
        loss_kernel<<<1, 384, 0, stream>>>(partials, (float*)d_out);
    }
}